// Round 6
// baseline (840.144 us; speedup 1.0000x reference)
//
#include <hip/hip_runtime.h>

#define NUM_NODES 20000
#define NUM_EDGES 320000
#define NODE_DIM  256
#define EDGE_DIM  64
#define HIDDEN    512

typedef short  s16x8  __attribute__((ext_vector_type(8)));
typedef float  f32x16 __attribute__((ext_vector_type(16)));
typedef unsigned short us16;

__device__ __forceinline__ us16 f2bf(float f) {
    union { float f; unsigned u; } c; c.f = f;
    unsigned r = c.u + 0x7fffu + ((c.u >> 16) & 1u);   // RNE
    return (us16)(r >> 16);
}
__device__ __forceinline__ float bf2f(us16 b) {
    union { unsigned u; float f; } c; c.u = ((unsigned)b) << 16;
    return c.f;
}
// swap bit2<->bit3: makes the 8 k-elements of an MFMA 32x32x16 A/B fragment
// contiguous in storage (HW-validated by round-2/3/4 PASS).
__device__ __forceinline__ int swapmid(int x) {
    return (x & 3) | ((x & 4) << 1) | ((x & 8) >> 1);
}
__device__ __forceinline__ void zero16(f32x16& a) {
    #pragma unroll
    for (int i = 0; i < 16; ++i) a[i] = 0.0f;
}
__device__ __forceinline__ void mfma3(f32x16& acc, s16x8 ah, s16x8 al, s16x8 bh, s16x8 bl) {
    acc = __builtin_amdgcn_mfma_f32_32x32x16_bf16(ah, bh, acc, 0, 0, 0);
    acc = __builtin_amdgcn_mfma_f32_32x32x16_bf16(ah, bl, acc, 0, 0, 0);
    acc = __builtin_amdgcn_mfma_f32_32x32x16_bf16(al, bh, acc, 0, 0, 0);
}
template<int STRIDE>
__device__ __forceinline__ void stash_quad(char* hi, char* lo, int r, int c, float4 v) {
    int cpp = (c & ~15) | swapmid(c & 15);      // c is 4-aligned -> quad stays contiguous
    int off = r * STRIDE + ((cpp * 2) ^ ((r & 7) << 4));
    us16 h0 = f2bf(v.x), h1 = f2bf(v.y), h2 = f2bf(v.z), h3 = f2bf(v.w);
    uint2 uh; uh.x = h0 | ((unsigned)h1 << 16); uh.y = h2 | ((unsigned)h3 << 16);
    uint2 ul;
    ul.x = f2bf(v.x - bf2f(h0)) | ((unsigned)f2bf(v.y - bf2f(h1)) << 16);
    ul.y = f2bf(v.z - bf2f(h2)) | ((unsigned)f2bf(v.w - bf2f(h3)) << 16);
    *reinterpret_cast<uint2*>(hi + off) = uh;
    *reinterpret_cast<uint2*>(lo + off) = ul;
}
template<int STRIDE>
__device__ __forceinline__ void bread(const char* hi, const char* lo, int r, int kbyte,
                                      s16x8& bh, s16x8& bl) {
    int off = r * STRIDE + (kbyte ^ ((r & 7) << 4));
    bh = *reinterpret_cast<const s16x8*>(hi + off);
    bl = *reinterpret_cast<const s16x8*>(lo + off);
}

// ---------------- CSR build ----------------
__global__ void build_deg(const int* __restrict__ tgt, int* __restrict__ deg) {
    int i = blockIdx.x * 256 + threadIdx.x;
    if (i < NUM_EDGES) atomicAdd(&deg[tgt[i]], 1);
}

// 20 elems/thread serial + one 1024-wide scan: ~12 barriers instead of ~400
__global__ void scan_deg(const int* __restrict__ deg, int* __restrict__ off) {
    __shared__ int sums[1024];
    const int tid  = threadIdx.x;
    const int base = tid * 20;                // 1024*20 = 20480 >= 20001
    int local[20];
    int s = 0;
    #pragma unroll
    for (int i = 0; i < 20; ++i) {
        local[i] = s;
        int idx = base + i;
        s += (idx < NUM_NODES) ? deg[idx] : 0;
    }
    sums[tid] = s;
    __syncthreads();
    for (int d = 1; d < 1024; d <<= 1) {      // inclusive Hillis-Steele
        int add = (tid >= d) ? sums[tid - d] : 0;
        __syncthreads();
        sums[tid] += add;
        __syncthreads();
    }
    const int chunk_off = sums[tid] - s;      // exclusive prefix of this chunk
    #pragma unroll
    for (int i = 0; i < 20; ++i) {
        int idx = base + i;
        if (idx <= NUM_NODES) off[idx] = chunk_off + local[i];
    }
}

__global__ void fill_csr(const int* __restrict__ tgt, const int* __restrict__ off,
                         int* __restrict__ cursor, int* __restrict__ csr) {
    int i = blockIdx.x * 256 + threadIdx.x;
    if (i < NUM_EDGES) {
        int t = tgt[i];
        int p = atomicAdd(&cursor[t], 1);
        csr[off[t] + p] = i;
    }
}

// ---------------- W23 = W2 @ W3b, b23 = b2 @ W3b (fp32) ----------------
__global__ void compute_w23(const float* __restrict__ W2, const float* __restrict__ b2,
                            const float* __restrict__ W3,
                            float* __restrict__ W23, float* __restrict__ b23) {
    int n = blockIdx.y * 256 + threadIdx.x;
    int i = blockIdx.x;
    const float* w3b = W3 + 256 * 512 + n;     // W3 rows 256.., stride 512
    float s = 0.f;
    if (i < 512) {
        const float* w2r = W2 + i * 512;
        for (int j = 0; j < 512; ++j) s = fmaf(w2r[j], w3b[(size_t)j * 512], s);
        W23[i * 512 + n] = s;
    } else {
        for (int j = 0; j < 512; ++j) s = fmaf(b2[j], w3b[(size_t)j * 512], s);
        b23[n] = s;
    }
}

// ---------------- weight planes: fp32 [K][N] -> bf16 hi/lo [kb][N][16perm] ----------------
__global__ void prep_planes(const float* __restrict__ W1, const float* __restrict__ W3,
                            const float* __restrict__ W4, const float* __restrict__ W23,
                            us16* __restrict__ wab_h, us16* __restrict__ wab_l,
                            us16* __restrict__ wc_h,  us16* __restrict__ wc_l,
                            us16* __restrict__ w34_h, us16* __restrict__ w34_l,
                            us16* __restrict__ w4_h,  us16* __restrict__ w4_l) {
    int idx = blockIdx.x * 256 + threadIdx.x;   // total 819200
    float w; us16 *dh, *dl; int k, n, N;
    if (idx < 262144) {                          // W1ab^T: K=256, N=1024
        n = idx & 1023; k = idx >> 10; N = 1024;
        w = W1[(k + (n >= 512 ? 256 : 0)) * 512 + (n & 511)];
        dh = wab_h; dl = wab_l;
    } else if (idx < 294912) {                   // W1c^T: K=64, N=512
        int j = idx - 262144; n = j & 511; k = j >> 9; N = 512;
        w = W1[(512 + k) * 512 + n];
        dh = wc_h; dl = wc_l;
    } else if (idx < 688128) {                   // [W3a; W23]^T: K=768, N=512
        int j = idx - 294912; n = j & 511; k = j >> 9; N = 512;
        w = (k < 256) ? W3[k * 512 + n] : W23[(k - 256) * 512 + n];
        dh = w34_h; dl = w34_l;
    } else {                                     // W4^T: K=512, N=256
        int j = idx - 688128; n = j & 255; k = j >> 8; N = 256;
        w = W4[k * 256 + n];
        dh = w4_h; dl = w4_l;
    }
    us16 h = f2bf(w);
    us16 l = f2bf(w - bf2f(h));
    int d = (k >> 4) * (N * 16) + n * 16 + swapmid(k & 15);
    dh[d] = h; dl[d] = l;
}

// ---------------- P = nf @ [W1a | W1b]  (20000 x 1024), 64-row tiles ----------------
__global__ __launch_bounds__(512, 2)
void gemm_p(const float* __restrict__ nf,
            const us16* __restrict__ wab_h, const us16* __restrict__ wab_l,
            float* __restrict__ P) {
    extern __shared__ char sB[];                 // 64 rows x 512B, hi @0 / lo @32768
    const int tid = threadIdx.x;
    const int nb  = blockIdx.x * 64;
    const int half = blockIdx.y;

    const float4* nf4 = reinterpret_cast<const float4*>(nf);
    for (int i = tid; i < 64 * 64; i += 512) {
        int r = i >> 6, q = i & 63;
        int row = nb + r; if (row >= NUM_NODES) row = NUM_NODES - 1;
        stash_quad<512>(sB, sB + 32768, r, 4 * q, nf4[(size_t)row * 64 + q]);
    }
    __syncthreads();

    const int w = tid >> 6, l = tid & 63, le = l & 31, g = l >> 5;
    const s16x8* Ah = reinterpret_cast<const s16x8*>(wab_h);
    const s16x8* Al = reinterpret_cast<const s16x8*>(wab_l);
    const int nbase = half * 512 + w * 64;

    f32x16 acc[2][2];                            // [mt][row-tile]
    #pragma unroll
    for (int a = 0; a < 2; ++a) { zero16(acc[a][0]); zero16(acc[a][1]); }

    for (int ks = 0; ks < 16; ++ks) {
        s16x8 AH[2], AL[2], bh[2], bl[2];
        #pragma unroll
        for (int mt = 0; mt < 2; ++mt) {
            int idx = ks * 2048 + (nbase + 32 * mt + le) * 2 + g;   // N=1024
            AH[mt] = Ah[idx]; AL[mt] = Al[idx];
        }
        #pragma unroll
        for (int rt = 0; rt < 2; ++rt)
            bread<512>(sB, sB + 32768, 32 * rt + le, ks * 32 + 16 * g, bh[rt], bl[rt]);
        #pragma unroll
        for (int mt = 0; mt < 2; ++mt)
            #pragma unroll
            for (int rt = 0; rt < 2; ++rt)
                mfma3(acc[mt][rt], AH[mt], AL[mt], bh[rt], bl[rt]);
    }

    float4* P4 = reinterpret_cast<float4*>(P);
    #pragma unroll
    for (int rt = 0; rt < 2; ++rt) {
        int row = nb + 32 * rt + le;
        if (row < NUM_NODES) {
            #pragma unroll
            for (int mt = 0; mt < 2; ++mt)
                #pragma unroll
                for (int rq = 0; rq < 4; ++rq) {
                    int nn = nbase + 32 * mt + 4 * g + 8 * rq;
                    float4 o = make_float4(acc[mt][rt][4*rq+0], acc[mt][rt][4*rq+1],
                                           acc[mt][rt][4*rq+2], acc[mt][rt][4*rq+3]);
                    P4[(size_t)row * 256 + (nn >> 2)] = o;
                }
        }
    }
}

// ---------------- edge kernel v3: pa[8] prefetched across the MFMA phase ----------------
__global__ __launch_bounds__(512, 2)
void edge_csr(const int* __restrict__ srcI, const int* __restrict__ tgtI,
              const int* __restrict__ csr, const float* __restrict__ ef,
              const us16* __restrict__ wc_h, const us16* __restrict__ wc_l,
              const float* __restrict__ b1, const float* __restrict__ P,
              float* __restrict__ aggH) {
    extern __shared__ char dsm[];                // sC fp32 32x2048B @0, ef tile @65536 (8192)
    char* sC = dsm;
    char* sB = dsm + 65536;
    __shared__ int sEid[64], sSrc[64], sTgt[64];

    const int tid  = threadIdx.x;
    const int orig = blockIdx.x;
    const int wg   = (orig & 7) * 625 + (orig >> 3);   // chunked XCD swizzle (5000 = 8*625)
    const int cb   = wg * 64;

    if (tid < 64) {
        int eid = csr[cb + tid];
        sEid[tid] = eid; sSrc[tid] = srcI[eid]; sTgt[tid] = tgtI[eid];
    }
    __syncthreads();

    const float4* ef4 = reinterpret_cast<const float4*>(ef);
    const float4* P4  = reinterpret_cast<const float4*>(P);
    const float4* b14 = reinterpret_cast<const float4*>(b1);
    const int w = tid >> 6, l = tid & 63, le = l & 31, g = l >> 5;
    const int grp = tid >> 7, slice = tid & 127;       // reduce-phase mapping
    const s16x8* Ah = reinterpret_cast<const s16x8*>(wc_h);
    const s16x8* Al = reinterpret_cast<const s16x8*>(wc_l);

    #pragma unroll
    for (int half = 0; half < 2; ++half) {
        const int e0 = half * 32 + grp * 8;
        // ef load first: stash's vmcnt wait retires it while pa stays in flight
        const int se = tid >> 4, sq = tid & 15;
        float4 efv = ef4[(size_t)sEid[half * 32 + se] * 16 + sq];
        // prefetch the reduce phase's P rows: 9 independent loads, consumed
        // after the MFMA phase (T14 async-split; latency hidden under MFMA)
        float4 pa[8];
        #pragma unroll
        for (int i = 0; i < 8; ++i)
            pa[i] = P4[(size_t)sSrc[e0 + i] * 256 + slice];
        float4 pt = P4[(size_t)sTgt[e0] * 256 + 128 + slice];
        stash_quad<128>(sB, sB + 4096, se, 4 * sq, efv);
        __syncthreads();

        // MFMA: C = ef @ W1c + b1 for this wave's 64 cols, 32 edges -> LDS
        #pragma unroll
        for (int mt = 0; mt < 2; ++mt) {
            f32x16 acc; zero16(acc);
            #pragma unroll
            for (int ks = 0; ks < 4; ++ks) {
                int idx = ks * 1024 + (w * 64 + 32 * mt + le) * 2 + g;   // N=512
                s16x8 bh, bl;
                bread<128>(sB, sB + 4096, le, ks * 32 + 16 * g, bh, bl);
                mfma3(acc, Ah[idx], Al[idx], bh, bl);
            }
            #pragma unroll
            for (int rq = 0; rq < 4; ++rq) {
                int h0 = w * 64 + 32 * mt + 4 * g + 8 * rq;
                float4 bq = b14[h0 >> 2];
                float4 v = make_float4(acc[4*rq+0] + bq.x, acc[4*rq+1] + bq.y,
                                       acc[4*rq+2] + bq.z, acc[4*rq+3] + bq.w);
                *reinterpret_cast<float4*>(sC + le * 2048 + ((h0 * 4) ^ ((le & 15) << 4))) = v;
            }
        }
        __syncthreads();

        {   // reduce: 128-thread groups sweep full rows; pa[] already resident
            float4 sum = make_float4(0.f, 0.f, 0.f, 0.f);
            int tcur = sTgt[e0];
            #pragma unroll
            for (int i = 0; i < 8; ++i) {
                int eg = e0 + i;
                int t = sTgt[eg];                    // uniform across the 128-thread group
                if (t != tcur) {
                    float* d = aggH + (size_t)tcur * 512 + slice * 4;
                    atomicAdd(d + 0, sum.x); atomicAdd(d + 1, sum.y);
                    atomicAdd(d + 2, sum.z); atomicAdd(d + 3, sum.w);
                    sum = make_float4(0.f, 0.f, 0.f, 0.f);
                    tcur = t;
                    pt = P4[(size_t)t * 256 + 128 + slice];
                }
                int crow = eg & 31;
                float4 c = *reinterpret_cast<const float4*>(
                    sC + crow * 2048 + ((slice * 16) ^ ((crow & 15) << 4)));
                sum.x += fmaxf(pa[i].x + pt.x + c.x, 0.f);
                sum.y += fmaxf(pa[i].y + pt.y + c.y, 0.f);
                sum.z += fmaxf(pa[i].z + pt.z + c.z, 0.f);
                sum.w += fmaxf(pa[i].w + pt.w + c.w, 0.f);
            }
            float* d = aggH + (size_t)tcur * 512 + slice * 4;
            atomicAdd(d + 0, sum.x); atomicAdd(d + 1, sum.y);
            atomicAdd(d + 2, sum.z); atomicAdd(d + 3, sum.w);
        }
        __syncthreads();
    }
}

// ---------------- node kernel: K-chunked double-buffered staging ----------------
__global__ __launch_bounds__(512, 2)
void node_mlp(const float* __restrict__ nf, const float* __restrict__ aggH,
              const int* __restrict__ deg,
              const us16* __restrict__ w34_h, const us16* __restrict__ w34_l,
              const us16* __restrict__ w4_h,  const us16* __restrict__ w4_l,
              const float* __restrict__ b3, const float* __restrict__ b23,
              const float* __restrict__ b4, float* __restrict__ out) {
    extern __shared__ char sm[];                 // buf0 @0, buf1 @32768 (each 32x256k hi/lo)
    __shared__ int sDeg[32];                     // H overlays @0..65536 after layer 3
    const int tid = threadIdx.x;
    const int nb  = blockIdx.x * 32;

    if (tid < 32) sDeg[tid] = deg[nb + tid];

    const float4* nf4 = reinterpret_cast<const float4*>(nf);
    const float4* ag4 = reinterpret_cast<const float4*>(aggH);
    auto stage = [&](int c, char* buf) {         // chunk c: k in [256c, 256c+256)
        for (int i = tid; i < 32 * 64; i += 512) {
            int r = i >> 6, q = i & 63;
            float4 v = (c == 0) ? nf4[(size_t)(nb + r) * 64 + q]
                                : ag4[(size_t)(nb + r) * 128 + (c - 1) * 64 + q];
            stash_quad<512>(buf, buf + 16384, r, 4 * q, v);
        }
    };

    stage(0, sm);
    __syncthreads();

    const int w = tid >> 6, l = tid & 63, le = l & 31, g = l >> 5;

    // layer 3: K=768 in 3 chunks of 256
    f32x16 acc[2]; zero16(acc[0]); zero16(acc[1]);
    {
        const s16x8* Ah = reinterpret_cast<const s16x8*>(w34_h);
        const s16x8* Al = reinterpret_cast<const s16x8*>(w34_l);
        #pragma unroll
        for (int c = 0; c < 3; ++c) {
            char* cur = sm + (c & 1) * 32768;
            char* oth = sm + ((c + 1) & 1) * 32768;
            if (c < 2) stage(c + 1, oth);        // overlap staging with MFMA
            #pragma unroll
            for (int ksl = 0; ksl < 16; ++ksl) {
                int ks = c * 16 + ksl;
                s16x8 AH[2], AL[2], bh, bl;
                #pragma unroll
                for (int mt = 0; mt < 2; ++mt) {
                    int idx = ks * 1024 + (w * 64 + 32 * mt + le) * 2 + g;   // N=512
                    AH[mt] = Ah[idx]; AL[mt] = Al[idx];
                }
                bread<512>(cur, cur + 16384, le, ksl * 32 + 16 * g, bh, bl);
                #pragma unroll
                for (int mt = 0; mt < 2; ++mt) mfma3(acc[mt], AH[mt], AL[mt], bh, bl);
            }
            __syncthreads();
        }
    }

    {   // bias + deg*b23 + relu -> H overlay (32 rows x 1024B stride, hi @0 / lo @32768)
        const float4* b34  = reinterpret_cast<const float4*>(b3);
        const float4* b234 = reinterpret_cast<const float4*>(b23);
        const float degv = (float)sDeg[le];
        #pragma unroll
        for (int mt = 0; mt < 2; ++mt)
            #pragma unroll
            for (int rq = 0; rq < 4; ++rq) {
                int hcol = w * 64 + 32 * mt + 4 * g + 8 * rq;
                float4 bq = b34[hcol >> 2], cq = b234[hcol >> 2];
                float4 gv;
                gv.x = fmaxf(acc[mt][4*rq+0] + bq.x + degv * cq.x, 0.f);
                gv.y = fmaxf(acc[mt][4*rq+1] + bq.y + degv * cq.y, 0.f);
                gv.z = fmaxf(acc[mt][4*rq+2] + bq.z + degv * cq.z, 0.f);
                gv.w = fmaxf(acc[mt][4*rq+3] + bq.w + degv * cq.w, 0.f);
                stash_quad<1024>(sm, sm + 32768, le, hcol, gv);
            }
    }
    __syncthreads();

    // layer 4: K=512, N=256 (one 32-col slice per wave)
    f32x16 a2; zero16(a2);
    {
        const s16x8* Ah = reinterpret_cast<const s16x8*>(w4_h);
        const s16x8* Al = reinterpret_cast<const s16x8*>(w4_l);
        for (int ks = 0; ks < 32; ++ks) {
            s16x8 AH, AL, bh, bl;
            int idx = ks * 512 + (w * 32 + le) * 2 + g;   // N=256
            AH = Ah[idx]; AL = Al[idx];
            bread<1024>(sm, sm + 32768, le, ks * 32 + 16 * g, bh, bl);
            mfma3(a2, AH, AL, bh, bl);
        }
    }

    const float4* b44 = reinterpret_cast<const float4*>(b4);
    float4* out4 = reinterpret_cast<float4*>(out);
    #pragma unroll
    for (int rq = 0; rq < 4; ++rq) {
        int n0 = w * 32 + 4 * g + 8 * rq;
        float4 bq  = b44[n0 >> 2];
        float4 res = nf4[(size_t)(nb + le) * 64 + (n0 >> 2)];
        float4 o;
        o.x = res.x + a2[4*rq+0] + bq.x;
        o.y = res.y + a2[4*rq+1] + bq.y;
        o.z = res.z + a2[4*rq+2] + bq.z;
        o.w = res.w + a2[4*rq+3] + bq.w;
        out4[(size_t)(nb + le) * 64 + (n0 >> 2)] = o;
    }
}

extern "C" void kernel_launch(void* const* d_in, const int* in_sizes, int n_in,
                              void* d_out, int out_size, void* d_ws, size_t ws_size,
                              hipStream_t stream) {
    const float* nf = (const float*)d_in[0];
    const int*   ei = (const int*)d_in[1];
    const float* ef = (const float*)d_in[2];
    const float* W1 = (const float*)d_in[3];
    const float* b1 = (const float*)d_in[4];
    const float* W2 = (const float*)d_in[5];
    const float* b2 = (const float*)d_in[6];
    const float* W3 = (const float*)d_in[7];
    const float* b3 = (const float*)d_in[8];
    const float* W4 = (const float*)d_in[9];
    const float* b4 = (const float*)d_in[10];
    float* out = (float*)d_out;

    // workspace layout (total ~128.7 MB)
    char* ws = (char*)d_ws;
    float* P      = (float*)(ws + 0);               // 20000x1024 fp32
    float* aggH   = (float*)(ws + 81920000);        // 20000x512  fp32
    us16*  wab_h  = (us16*)(ws + 122880000);
    us16*  wab_l  = (us16*)(ws + 123404288);
    us16*  wc_h   = (us16*)(ws + 123928576);
    us16*  wc_l   = (us16*)(ws + 123994112);
    us16*  w34_h  = (us16*)(ws + 124059648);
    us16*  w34_l  = (us16*)(ws + 124846080);
    us16*  w4_h   = (us16*)(ws + 125632512);
    us16*  w4_l   = (us16*)(ws + 125894656);
    float* W23    = (float*)(ws + 126156800);       // 512x512 fp32
    float* b23    = (float*)(ws + 127205376);       // 512 fp32
    int*   deg    = (int*)  (ws + 127207424);       // 20000
    int*   cursor = (int*)  (ws + 127287424);       // 20000
    int*   offs   = (int*)  (ws + 127367424);       // 20001
    int*   csr    = (int*)  (ws + 127447440);       // 320000

    const int* src = ei;                 // edge_index[0]
    const int* tgt = ei + NUM_EDGES;     // edge_index[1]

    (void)hipFuncSetAttribute(reinterpret_cast<const void*>(&edge_csr),
                              hipFuncAttributeMaxDynamicSharedMemorySize, 73728);
    (void)hipFuncSetAttribute(reinterpret_cast<const void*>(&node_mlp),
                              hipFuncAttributeMaxDynamicSharedMemorySize, 65536);
    (void)hipFuncSetAttribute(reinterpret_cast<const void*>(&gemm_p),
                              hipFuncAttributeMaxDynamicSharedMemorySize, 65536);

    hipMemsetAsync(deg, 0, 160000, stream);                       // deg + cursor
    hipMemsetAsync(aggH, 0, (size_t)NUM_NODES * HIDDEN * 4, stream);

    build_deg<<<1250, 256, 0, stream>>>(tgt, deg);
    scan_deg<<<1, 1024, 0, stream>>>(deg, offs);
    fill_csr<<<1250, 256, 0, stream>>>(tgt, offs, cursor, csr);

    compute_w23<<<dim3(513, 2), 256, 0, stream>>>(W2, b2, W3, W23, b23);
    prep_planes<<<3200, 256, 0, stream>>>(W1, W3, W4, W23,
                                          wab_h, wab_l, wc_h, wc_l,
                                          w34_h, w34_l, w4_h, w4_l);

    gemm_p<<<dim3(313, 2), 512, 65536, stream>>>(nf, wab_h, wab_l, P);
    edge_csr<<<5000, 512, 73728, stream>>>(src, tgt, csr, ef, wc_h, wc_l, b1, P, aggH);
    node_mlp<<<625, 512, 65536, stream>>>(nf, aggH, deg, w34_h, w34_l,
                                          w4_h, w4_l, b3, b23, b4, out);
}

// Round 7
// 807.821 us; speedup vs baseline: 1.0400x; 1.0400x over previous
//
#include <hip/hip_runtime.h>

#define NUM_NODES 20000
#define NUM_EDGES 320000
#define NODE_DIM  256
#define EDGE_DIM  64
#define HIDDEN    512

typedef short  s16x8  __attribute__((ext_vector_type(8)));
typedef float  f32x16 __attribute__((ext_vector_type(16)));
typedef unsigned short us16;

__device__ __forceinline__ us16 f2bf(float f) {
    union { float f; unsigned u; } c; c.f = f;
    unsigned r = c.u + 0x7fffu + ((c.u >> 16) & 1u);   // RNE
    return (us16)(r >> 16);
}
__device__ __forceinline__ float bf2f(us16 b) {
    union { unsigned u; float f; } c; c.u = ((unsigned)b) << 16;
    return c.f;
}
// swap bit2<->bit3: makes the 8 k-elements of an MFMA 32x32x16 A/B fragment
// contiguous in storage (HW-validated by round-2/3/4 PASS).
__device__ __forceinline__ int swapmid(int x) {
    return (x & 3) | ((x & 4) << 1) | ((x & 8) >> 1);
}
__device__ __forceinline__ void zero16(f32x16& a) {
    #pragma unroll
    for (int i = 0; i < 16; ++i) a[i] = 0.0f;
}
__device__ __forceinline__ void mfma3(f32x16& acc, s16x8 ah, s16x8 al, s16x8 bh, s16x8 bl) {
    acc = __builtin_amdgcn_mfma_f32_32x32x16_bf16(ah, bh, acc, 0, 0, 0);
    acc = __builtin_amdgcn_mfma_f32_32x32x16_bf16(ah, bl, acc, 0, 0, 0);
    acc = __builtin_amdgcn_mfma_f32_32x32x16_bf16(al, bh, acc, 0, 0, 0);
}
template<int STRIDE>
__device__ __forceinline__ void stash_quad(char* hi, char* lo, int r, int c, float4 v) {
    int cpp = (c & ~15) | swapmid(c & 15);      // c is 4-aligned -> quad stays contiguous
    int off = r * STRIDE + ((cpp * 2) ^ ((r & 7) << 4));
    us16 h0 = f2bf(v.x), h1 = f2bf(v.y), h2 = f2bf(v.z), h3 = f2bf(v.w);
    uint2 uh; uh.x = h0 | ((unsigned)h1 << 16); uh.y = h2 | ((unsigned)h3 << 16);
    uint2 ul;
    ul.x = f2bf(v.x - bf2f(h0)) | ((unsigned)f2bf(v.y - bf2f(h1)) << 16);
    ul.y = f2bf(v.z - bf2f(h2)) | ((unsigned)f2bf(v.w - bf2f(h3)) << 16);
    *reinterpret_cast<uint2*>(hi + off) = uh;
    *reinterpret_cast<uint2*>(lo + off) = ul;
}
template<int STRIDE>
__device__ __forceinline__ void bread(const char* hi, const char* lo, int r, int kbyte,
                                      s16x8& bh, s16x8& bl) {
    int off = r * STRIDE + (kbyte ^ ((r & 7) << 4));
    bh = *reinterpret_cast<const s16x8*>(hi + off);
    bl = *reinterpret_cast<const s16x8*>(lo + off);
}

// ---------------- CSR build ----------------
__global__ void build_deg(const int* __restrict__ tgt, int* __restrict__ deg) {
    int i = blockIdx.x * 256 + threadIdx.x;
    if (i < NUM_EDGES) atomicAdd(&deg[tgt[i]], 1);
}

// 20 elems/thread serial + one 1024-wide scan: ~12 barriers instead of ~400
__global__ void scan_deg(const int* __restrict__ deg, int* __restrict__ off) {
    __shared__ int sums[1024];
    const int tid  = threadIdx.x;
    const int base = tid * 20;                // 1024*20 = 20480 >= 20001
    int local[20];
    int s = 0;
    #pragma unroll
    for (int i = 0; i < 20; ++i) {
        local[i] = s;
        int idx = base + i;
        s += (idx < NUM_NODES) ? deg[idx] : 0;
    }
    sums[tid] = s;
    __syncthreads();
    for (int d = 1; d < 1024; d <<= 1) {      // inclusive Hillis-Steele
        int add = (tid >= d) ? sums[tid - d] : 0;
        __syncthreads();
        sums[tid] += add;
        __syncthreads();
    }
    const int chunk_off = sums[tid] - s;      // exclusive prefix of this chunk
    #pragma unroll
    for (int i = 0; i < 20; ++i) {
        int idx = base + i;
        if (idx <= NUM_NODES) off[idx] = chunk_off + local[i];
    }
}

__global__ void fill_csr(const int* __restrict__ tgt, const int* __restrict__ off,
                         int* __restrict__ cursor, int* __restrict__ csr) {
    int i = blockIdx.x * 256 + threadIdx.x;
    if (i < NUM_EDGES) {
        int t = tgt[i];
        int p = atomicAdd(&cursor[t], 1);
        csr[off[t] + p] = i;
    }
}

// ---------------- W23 = W2 @ W3b, b23 = b2 @ W3b (fp32) ----------------
__global__ void compute_w23(const float* __restrict__ W2, const float* __restrict__ b2,
                            const float* __restrict__ W3,
                            float* __restrict__ W23, float* __restrict__ b23) {
    int n = blockIdx.y * 256 + threadIdx.x;
    int i = blockIdx.x;
    const float* w3b = W3 + 256 * 512 + n;     // W3 rows 256.., stride 512
    float s = 0.f;
    if (i < 512) {
        const float* w2r = W2 + i * 512;
        for (int j = 0; j < 512; ++j) s = fmaf(w2r[j], w3b[(size_t)j * 512], s);
        W23[i * 512 + n] = s;
    } else {
        for (int j = 0; j < 512; ++j) s = fmaf(b2[j], w3b[(size_t)j * 512], s);
        b23[n] = s;
    }
}

// ---------------- weight planes: fp32 [K][N] -> bf16 hi/lo [kb][N][16perm] ----------------
__global__ void prep_planes(const float* __restrict__ W1, const float* __restrict__ W3,
                            const float* __restrict__ W4, const float* __restrict__ W23,
                            us16* __restrict__ wab_h, us16* __restrict__ wab_l,
                            us16* __restrict__ wc_h,  us16* __restrict__ wc_l,
                            us16* __restrict__ w34_h, us16* __restrict__ w34_l,
                            us16* __restrict__ w4_h,  us16* __restrict__ w4_l) {
    int idx = blockIdx.x * 256 + threadIdx.x;   // total 819200
    float w; us16 *dh, *dl; int k, n, N;
    if (idx < 262144) {                          // W1ab^T: K=256, N=1024
        n = idx & 1023; k = idx >> 10; N = 1024;
        w = W1[(k + (n >= 512 ? 256 : 0)) * 512 + (n & 511)];
        dh = wab_h; dl = wab_l;
    } else if (idx < 294912) {                   // W1c^T: K=64, N=512
        int j = idx - 262144; n = j & 511; k = j >> 9; N = 512;
        w = W1[(512 + k) * 512 + n];
        dh = wc_h; dl = wc_l;
    } else if (idx < 688128) {                   // [W3a; W23]^T: K=768, N=512
        int j = idx - 294912; n = j & 511; k = j >> 9; N = 512;
        w = (k < 256) ? W3[k * 512 + n] : W23[(k - 256) * 512 + n];
        dh = w34_h; dl = w34_l;
    } else {                                     // W4^T: K=512, N=256
        int j = idx - 688128; n = j & 255; k = j >> 8; N = 256;
        w = W4[k * 256 + n];
        dh = w4_h; dl = w4_l;
    }
    us16 h = f2bf(w);
    us16 l = f2bf(w - bf2f(h));
    int d = (k >> 4) * (N * 16) + n * 16 + swapmid(k & 15);
    dh[d] = h; dl[d] = l;
}

// ---------------- P = nf @ [W1a | W1b]  (20000 x 1024), 64-row tiles ----------------
__global__ __launch_bounds__(512, 2)
void gemm_p(const float* __restrict__ nf,
            const us16* __restrict__ wab_h, const us16* __restrict__ wab_l,
            float* __restrict__ P) {
    extern __shared__ char sB[];                 // 64 rows x 512B, hi @0 / lo @32768
    const int tid = threadIdx.x;
    const int nb  = blockIdx.x * 64;
    const int half = blockIdx.y;

    const float4* nf4 = reinterpret_cast<const float4*>(nf);
    for (int i = tid; i < 64 * 64; i += 512) {
        int r = i >> 6, q = i & 63;
        int row = nb + r; if (row >= NUM_NODES) row = NUM_NODES - 1;
        stash_quad<512>(sB, sB + 32768, r, 4 * q, nf4[(size_t)row * 64 + q]);
    }
    __syncthreads();

    const int w = tid >> 6, l = tid & 63, le = l & 31, g = l >> 5;
    const s16x8* Ah = reinterpret_cast<const s16x8*>(wab_h);
    const s16x8* Al = reinterpret_cast<const s16x8*>(wab_l);
    const int nbase = half * 512 + w * 64;

    f32x16 acc[2][2];                            // [mt][row-tile]
    #pragma unroll
    for (int a = 0; a < 2; ++a) { zero16(acc[a][0]); zero16(acc[a][1]); }

    for (int ks = 0; ks < 16; ++ks) {
        s16x8 AH[2], AL[2], bh[2], bl[2];
        #pragma unroll
        for (int mt = 0; mt < 2; ++mt) {
            int idx = ks * 2048 + (nbase + 32 * mt + le) * 2 + g;   // N=1024
            AH[mt] = Ah[idx]; AL[mt] = Al[idx];
        }
        #pragma unroll
        for (int rt = 0; rt < 2; ++rt)
            bread<512>(sB, sB + 32768, 32 * rt + le, ks * 32 + 16 * g, bh[rt], bl[rt]);
        #pragma unroll
        for (int mt = 0; mt < 2; ++mt)
            #pragma unroll
            for (int rt = 0; rt < 2; ++rt)
                mfma3(acc[mt][rt], AH[mt], AL[mt], bh[rt], bl[rt]);
    }

    float4* P4 = reinterpret_cast<float4*>(P);
    #pragma unroll
    for (int rt = 0; rt < 2; ++rt) {
        int row = nb + 32 * rt + le;
        if (row < NUM_NODES) {
            #pragma unroll
            for (int mt = 0; mt < 2; ++mt)
                #pragma unroll
                for (int rq = 0; rq < 4; ++rq) {
                    int nn = nbase + 32 * mt + 4 * g + 8 * rq;
                    float4 o = make_float4(acc[mt][rt][4*rq+0], acc[mt][rt][4*rq+1],
                                           acc[mt][rt][4*rq+2], acc[mt][rt][4*rq+3]);
                    P4[(size_t)row * 256 + (nn >> 2)] = o;
                }
        }
    }
}

// ---------------- edge kernel v4: pa[8] batch-issued INSIDE the reduce region ----------------
// r6 lesson: loads issued before a __syncthreads are drained at the barrier
// (compiler emits s_waitcnt vmcnt(0) before s_barrier) — prefetch across
// barriers is impossible at HIP level. Instead batch-issue all 8 independent
// loads at reduce-region entry: 8 outstanding, first-use latency paid once.
__global__ __launch_bounds__(512, 4)
void edge_csr(const int* __restrict__ srcI, const int* __restrict__ tgtI,
              const int* __restrict__ csr, const float* __restrict__ ef,
              const us16* __restrict__ wc_h, const us16* __restrict__ wc_l,
              const float* __restrict__ b1, const float* __restrict__ P,
              float* __restrict__ aggH) {
    extern __shared__ char dsm[];                // sC fp32 32x2048B @0, ef tile @65536 (8192)
    char* sC = dsm;
    char* sB = dsm + 65536;
    __shared__ int sEid[64], sSrc[64], sTgt[64];

    const int tid  = threadIdx.x;
    const int orig = blockIdx.x;
    const int wg   = (orig & 7) * 625 + (orig >> 3);   // chunked XCD swizzle (5000 = 8*625)
    const int cb   = wg * 64;

    if (tid < 64) {
        int eid = csr[cb + tid];
        sEid[tid] = eid; sSrc[tid] = srcI[eid]; sTgt[tid] = tgtI[eid];
    }
    __syncthreads();

    const float4* ef4 = reinterpret_cast<const float4*>(ef);
    const float4* P4  = reinterpret_cast<const float4*>(P);
    const float4* b14 = reinterpret_cast<const float4*>(b1);
    const int w = tid >> 6, l = tid & 63, le = l & 31, g = l >> 5;
    const int grp = tid >> 7, slice = tid & 127;       // reduce-phase mapping
    const s16x8* Ah = reinterpret_cast<const s16x8*>(wc_h);
    const s16x8* Al = reinterpret_cast<const s16x8*>(wc_l);

    #pragma unroll
    for (int half = 0; half < 2; ++half) {
        const int e0 = half * 32 + grp * 8;
        {   // stage ef half-tile: exactly one quad per thread (32 edges x 16 quads)
            const int se = tid >> 4, sq = tid & 15;
            stash_quad<128>(sB, sB + 4096, se, 4 * sq,
                            ef4[(size_t)sEid[half * 32 + se] * 16 + sq]);
        }
        __syncthreads();

        // MFMA: C = ef @ W1c + b1 for this wave's 64 cols, 32 edges -> LDS
        #pragma unroll
        for (int mt = 0; mt < 2; ++mt) {
            f32x16 acc; zero16(acc);
            #pragma unroll
            for (int ks = 0; ks < 4; ++ks) {
                int idx = ks * 1024 + (w * 64 + 32 * mt + le) * 2 + g;   // N=512
                s16x8 bh, bl;
                bread<128>(sB, sB + 4096, le, ks * 32 + 16 * g, bh, bl);
                mfma3(acc, Ah[idx], Al[idx], bh, bl);
            }
            #pragma unroll
            for (int rq = 0; rq < 4; ++rq) {
                int h0 = w * 64 + 32 * mt + 4 * g + 8 * rq;
                float4 bq = b14[h0 >> 2];
                float4 v = make_float4(acc[4*rq+0] + bq.x, acc[4*rq+1] + bq.y,
                                       acc[4*rq+2] + bq.z, acc[4*rq+3] + bq.w);
                *reinterpret_cast<float4*>(sC + le * 2048 + ((h0 * 4) ^ ((le & 15) << 4))) = v;
            }
        }
        __syncthreads();

        {   // reduce: batch-issue all 8 pa loads, then walk (loads pipelined)
            float4 pa[8];
            #pragma unroll
            for (int i = 0; i < 8; ++i)
                pa[i] = P4[(size_t)sSrc[e0 + i] * 256 + slice];
            int tcur = sTgt[e0];
            float4 pt = P4[(size_t)tcur * 256 + 128 + slice];
            float4 sum = make_float4(0.f, 0.f, 0.f, 0.f);
            #pragma unroll
            for (int i = 0; i < 8; ++i) {
                int eg = e0 + i;
                int t = sTgt[eg];                    // uniform across the 128-thread group
                if (t != tcur) {
                    float* d = aggH + (size_t)tcur * 512 + slice * 4;
                    atomicAdd(d + 0, sum.x); atomicAdd(d + 1, sum.y);
                    atomicAdd(d + 2, sum.z); atomicAdd(d + 3, sum.w);
                    sum = make_float4(0.f, 0.f, 0.f, 0.f);
                    tcur = t;
                    pt = P4[(size_t)t * 256 + 128 + slice];
                }
                int crow = eg & 31;
                float4 c = *reinterpret_cast<const float4*>(
                    sC + crow * 2048 + ((slice * 16) ^ ((crow & 15) << 4)));
                sum.x += fmaxf(pa[i].x + pt.x + c.x, 0.f);
                sum.y += fmaxf(pa[i].y + pt.y + c.y, 0.f);
                sum.z += fmaxf(pa[i].z + pt.z + c.z, 0.f);
                sum.w += fmaxf(pa[i].w + pt.w + c.w, 0.f);
            }
            float* d = aggH + (size_t)tcur * 512 + slice * 4;
            atomicAdd(d + 0, sum.x); atomicAdd(d + 1, sum.y);
            atomicAdd(d + 2, sum.z); atomicAdd(d + 3, sum.w);
        }
        __syncthreads();
    }
}

// ---------------- node kernel: K-chunked double-buffered staging ----------------
__global__ __launch_bounds__(512, 2)
void node_mlp(const float* __restrict__ nf, const float* __restrict__ aggH,
              const int* __restrict__ deg,
              const us16* __restrict__ w34_h, const us16* __restrict__ w34_l,
              const us16* __restrict__ w4_h,  const us16* __restrict__ w4_l,
              const float* __restrict__ b3, const float* __restrict__ b23,
              const float* __restrict__ b4, float* __restrict__ out) {
    extern __shared__ char sm[];                 // buf0 @0, buf1 @32768 (each 32x256k hi/lo)
    __shared__ int sDeg[32];                     // H overlays @0..65536 after layer 3
    const int tid = threadIdx.x;
    const int nb  = blockIdx.x * 32;

    if (tid < 32) sDeg[tid] = deg[nb + tid];

    const float4* nf4 = reinterpret_cast<const float4*>(nf);
    const float4* ag4 = reinterpret_cast<const float4*>(aggH);
    auto stage = [&](int c, char* buf) {         // chunk c: k in [256c, 256c+256)
        for (int i = tid; i < 32 * 64; i += 512) {
            int r = i >> 6, q = i & 63;
            float4 v = (c == 0) ? nf4[(size_t)(nb + r) * 64 + q]
                                : ag4[(size_t)(nb + r) * 128 + (c - 1) * 64 + q];
            stash_quad<512>(buf, buf + 16384, r, 4 * q, v);
        }
    };

    stage(0, sm);
    __syncthreads();

    const int w = tid >> 6, l = tid & 63, le = l & 31, g = l >> 5;

    // layer 3: K=768 in 3 chunks of 256
    f32x16 acc[2]; zero16(acc[0]); zero16(acc[1]);
    {
        const s16x8* Ah = reinterpret_cast<const s16x8*>(w34_h);
        const s16x8* Al = reinterpret_cast<const s16x8*>(w34_l);
        #pragma unroll
        for (int c = 0; c < 3; ++c) {
            char* cur = sm + (c & 1) * 32768;
            char* oth = sm + ((c + 1) & 1) * 32768;
            if (c < 2) stage(c + 1, oth);        // overlap staging with MFMA
            #pragma unroll
            for (int ksl = 0; ksl < 16; ++ksl) {
                int ks = c * 16 + ksl;
                s16x8 AH[2], AL[2], bh, bl;
                #pragma unroll
                for (int mt = 0; mt < 2; ++mt) {
                    int idx = ks * 1024 + (w * 64 + 32 * mt + le) * 2 + g;   // N=512
                    AH[mt] = Ah[idx]; AL[mt] = Al[idx];
                }
                bread<512>(cur, cur + 16384, le, ksl * 32 + 16 * g, bh, bl);
                #pragma unroll
                for (int mt = 0; mt < 2; ++mt) mfma3(acc[mt], AH[mt], AL[mt], bh, bl);
            }
            __syncthreads();
        }
    }

    {   // bias + deg*b23 + relu -> H overlay (32 rows x 1024B stride, hi @0 / lo @32768)
        const float4* b34  = reinterpret_cast<const float4*>(b3);
        const float4* b234 = reinterpret_cast<const float4*>(b23);
        const float degv = (float)sDeg[le];
        #pragma unroll
        for (int mt = 0; mt < 2; ++mt)
            #pragma unroll
            for (int rq = 0; rq < 4; ++rq) {
                int hcol = w * 64 + 32 * mt + 4 * g + 8 * rq;
                float4 bq = b34[hcol >> 2], cq = b234[hcol >> 2];
                float4 gv;
                gv.x = fmaxf(acc[mt][4*rq+0] + bq.x + degv * cq.x, 0.f);
                gv.y = fmaxf(acc[mt][4*rq+1] + bq.y + degv * cq.y, 0.f);
                gv.z = fmaxf(acc[mt][4*rq+2] + bq.z + degv * cq.z, 0.f);
                gv.w = fmaxf(acc[mt][4*rq+3] + bq.w + degv * cq.w, 0.f);
                stash_quad<1024>(sm, sm + 32768, le, hcol, gv);
            }
    }
    __syncthreads();

    // layer 4: K=512, N=256 (one 32-col slice per wave)
    f32x16 a2; zero16(a2);
    {
        const s16x8* Ah = reinterpret_cast<const s16x8*>(w4_h);
        const s16x8* Al = reinterpret_cast<const s16x8*>(w4_l);
        for (int ks = 0; ks < 32; ++ks) {
            s16x8 AH, AL, bh, bl;
            int idx = ks * 512 + (w * 32 + le) * 2 + g;   // N=256
            AH = Ah[idx]; AL = Al[idx];
            bread<1024>(sm, sm + 32768, le, ks * 32 + 16 * g, bh, bl);
            mfma3(a2, AH, AL, bh, bl);
        }
    }

    const float4* b44 = reinterpret_cast<const float4*>(b4);
    float4* out4 = reinterpret_cast<float4*>(out);
    #pragma unroll
    for (int rq = 0; rq < 4; ++rq) {
        int n0 = w * 32 + 4 * g + 8 * rq;
        float4 bq  = b44[n0 >> 2];
        float4 res = nf4[(size_t)(nb + le) * 64 + (n0 >> 2)];
        float4 o;
        o.x = res.x + a2[4*rq+0] + bq.x;
        o.y = res.y + a2[4*rq+1] + bq.y;
        o.z = res.z + a2[4*rq+2] + bq.z;
        o.w = res.w + a2[4*rq+3] + bq.w;
        out4[(size_t)(nb + le) * 64 + (n0 >> 2)] = o;
    }
}

extern "C" void kernel_launch(void* const* d_in, const int* in_sizes, int n_in,
                              void* d_out, int out_size, void* d_ws, size_t ws_size,
                              hipStream_t stream) {
    const float* nf = (const float*)d_in[0];
    const int*   ei = (const int*)d_in[1];
    const float* ef = (const float*)d_in[2];
    const float* W1 = (const float*)d_in[3];
    const float* b1 = (const float*)d_in[4];
    const float* W2 = (const float*)d_in[5];
    const float* b2 = (const float*)d_in[6];
    const float* W3 = (const float*)d_in[7];
    const float* b3 = (const float*)d_in[8];
    const float* W4 = (const float*)d_in[9];
    const float* b4 = (const float*)d_in[10];
    float* out = (float*)d_out;

    // workspace layout (total ~128.7 MB)
    char* ws = (char*)d_ws;
    float* P      = (float*)(ws + 0);               // 20000x1024 fp32
    float* aggH   = (float*)(ws + 81920000);        // 20000x512  fp32
    us16*  wab_h  = (us16*)(ws + 122880000);
    us16*  wab_l  = (us16*)(ws + 123404288);
    us16*  wc_h   = (us16*)(ws + 123928576);
    us16*  wc_l   = (us16*)(ws + 123994112);
    us16*  w34_h  = (us16*)(ws + 124059648);
    us16*  w34_l  = (us16*)(ws + 124846080);
    us16*  w4_h   = (us16*)(ws + 125632512);
    us16*  w4_l   = (us16*)(ws + 125894656);
    float* W23    = (float*)(ws + 126156800);       // 512x512 fp32
    float* b23    = (float*)(ws + 127205376);       // 512 fp32
    int*   deg    = (int*)  (ws + 127207424);       // 20000
    int*   cursor = (int*)  (ws + 127287424);       // 20000
    int*   offs   = (int*)  (ws + 127367424);       // 20001
    int*   csr    = (int*)  (ws + 127447440);       // 320000

    const int* src = ei;                 // edge_index[0]
    const int* tgt = ei + NUM_EDGES;     // edge_index[1]

    (void)hipFuncSetAttribute(reinterpret_cast<const void*>(&edge_csr),
                              hipFuncAttributeMaxDynamicSharedMemorySize, 73728);
    (void)hipFuncSetAttribute(reinterpret_cast<const void*>(&node_mlp),
                              hipFuncAttributeMaxDynamicSharedMemorySize, 65536);
    (void)hipFuncSetAttribute(reinterpret_cast<const void*>(&gemm_p),
                              hipFuncAttributeMaxDynamicSharedMemorySize, 65536);

    hipMemsetAsync(deg, 0, 160000, stream);                       // deg + cursor
    hipMemsetAsync(aggH, 0, (size_t)NUM_NODES * HIDDEN * 4, stream);

    build_deg<<<1250, 256, 0, stream>>>(tgt, deg);
    scan_deg<<<1, 1024, 0, stream>>>(deg, offs);
    fill_csr<<<1250, 256, 0, stream>>>(tgt, offs, cursor, csr);

    compute_w23<<<dim3(513, 2), 256, 0, stream>>>(W2, b2, W3, W23, b23);
    prep_planes<<<3200, 256, 0, stream>>>(W1, W3, W4, W23,
                                          wab_h, wab_l, wc_h, wc_l,
                                          w34_h, w34_l, w4_h, w4_l);

    gemm_p<<<dim3(313, 2), 512, 65536, stream>>>(nf, wab_h, wab_l, P);
    edge_csr<<<5000, 512, 73728, stream>>>(src, tgt, csr, ef, wc_h, wc_l, b1, P, aggH);
    node_mlp<<<625, 512, 65536, stream>>>(nf, aggH, deg, w34_h, w34_l,
                                          w4_h, w4_l, b3, b23, b4, out);
}